// Round 12
// baseline (1188.577 us; speedup 1.0000x reference)
//
#include <hip/hip_runtime.h>
#include <math.h>

typedef unsigned short u16;
typedef unsigned int u32;
typedef __attribute__((ext_vector_type(8))) short bf16x8;
typedef __attribute__((ext_vector_type(4))) float f32x4;
typedef __attribute__((ext_vector_type(2))) float f32x2;

constexpr float EPS_BN = 1e-5f;
constexpr float NEG = 0.1f;
constexpr int LDP = 800;   // leading dim of psum/psq: [feature][chunk<=LDP]

static inline int cdiv(int a, int b) { return (a + b - 1) / b; }

// ---------------- bf16 helpers ----------------

__device__ __forceinline__ float b2f_lo(u32 v) { return __uint_as_float(v << 16); }
__device__ __forceinline__ float b2f_hi(u32 v) { return __uint_as_float(v & 0xFFFF0000u); }
__device__ __forceinline__ float b2f(u16 v) { return __uint_as_float(((u32)v) << 16); }
__device__ __forceinline__ u16 f2b(float f) {
  u32 u = __float_as_uint(f);
  u32 r = u + 0x7FFFu + ((u >> 16) & 1u);
  return (u16)(r >> 16);
}
__device__ __forceinline__ u32 pack2(float a, float b) {
  return (u32)f2b(a) | ((u32)f2b(b) << 16);
}
__device__ __forceinline__ void unpack8(uint4 v, float* o) {
  o[0] = b2f_lo(v.x); o[1] = b2f_hi(v.x);
  o[2] = b2f_lo(v.y); o[3] = b2f_hi(v.y);
  o[4] = b2f_lo(v.z); o[5] = b2f_hi(v.z);
  o[6] = b2f_lo(v.w); o[7] = b2f_hi(v.w);
}

__device__ __forceinline__ void gload16(const void* g, void* l) {
  __builtin_amdgcn_global_load_lds(
      (const __attribute__((address_space(1))) u32*)g,
      (__attribute__((address_space(3))) u32*)l, 16, 0, 0);
}

// packed BN+lrelu+accumulate: acc[p] += d * lrelu(z*sc+sh), 8 feats (4 pairs)
__device__ __forceinline__ void bn8_acc(uint4 v, const f32x2* sc2, const f32x2* sh2,
                                        float d, f32x2* acc) {
  const f32x2 dd = {d, d};
  const f32x2 c01 = {NEG, NEG};
  const u32* w = &v.x;
#pragma unroll
  for (int p = 0; p < 4; ++p) {
    f32x2 z = {b2f_lo(w[p]), b2f_hi(w[p])};
    f32x2 t = z * sc2[p] + sh2[p];                       // v_pk_fma
    f32x2 q = __builtin_elementwise_max(t, t * c01);     // v_pk_mul + v_pk_max
    acc[p] = dd * q + acc[p];                            // v_pk_fma
  }
}

// ---------------- CSR build (bucketed, packed ebuf) ----------------

__global__ __launch_bounds__(256) void k_bcount(const int* __restrict__ dst,
                                                int* __restrict__ bucketCnt, int E) {
  __shared__ int hist[256];
  int tid = threadIdx.x;
  hist[tid] = 0;
  __syncthreads();
  int e0 = blockIdx.x * 4096;
#pragma unroll
  for (int i = 0; i < 16; ++i) {
    int e = e0 + i * 256 + tid;
    if (e < E) atomicAdd(&hist[dst[e] >> 9], 1);
  }
  __syncthreads();
  int h = hist[tid];
  if (h > 0) atomicAdd(&bucketCnt[tid], h);
}

__global__ void k_bscan(const int* __restrict__ bucketCnt, int* __restrict__ bucketOff,
                        int* __restrict__ bucketCur, int NB, int E) {
  __shared__ int s[256];
  int tid = threadIdx.x;
  int v = (tid < NB) ? bucketCnt[tid] : 0;
  s[tid] = v;
  __syncthreads();
  for (int off = 1; off < 256; off <<= 1) {
    int t = (tid >= off) ? s[tid - off] : 0;
    __syncthreads();
    s[tid] += t;
    __syncthreads();
  }
  if (tid < NB) bucketOff[tid] = s[tid] - v;
  if (tid == NB) bucketOff[NB] = E;
  if (tid < NB) bucketCur[tid] = 0;
}

__global__ __launch_bounds__(256) void k_bucket(const int* __restrict__ src,
                                                const int* __restrict__ dst,
                                                const int* __restrict__ bucketOff,
                                                int* __restrict__ bucketCur,
                                                u32* __restrict__ ebuf, int E) {
  __shared__ int hist[256];
  __shared__ int base[256];
  __shared__ int lcur[256];
  int tid = threadIdx.x;
  hist[tid] = 0; lcur[tid] = 0;
  __syncthreads();
  int e0 = blockIdx.x * 4096;
  int ss[16], dd[16];
#pragma unroll
  for (int i = 0; i < 16; ++i) {
    int e = e0 + i * 256 + tid;
    if (e < E) {
      ss[i] = src[e]; dd[i] = dst[e];
      atomicAdd(&hist[dd[i] >> 9], 1);
    } else dd[i] = -1;
  }
  __syncthreads();
  int h = hist[tid];
  if (h > 0) base[tid] = bucketOff[tid] + atomicAdd(&bucketCur[tid], h);
  __syncthreads();
#pragma unroll
  for (int i = 0; i < 16; ++i) {
    if (dd[i] >= 0) {
      int bk = dd[i] >> 9;
      int p = atomicAdd(&lcur[bk], 1);
      ebuf[base[bk] + p] = ((u32)ss[i] << 9) | ((u32)dd[i] & 511u);
    }
  }
}

// per-bucket CSR finalize + dis + xd(bf16) = dis*x
__global__ __launch_bounds__(256) void k_csr(const u32* __restrict__ ebuf,
                                             const int* __restrict__ bucketOff,
                                             const float* __restrict__ x,
                                             int* __restrict__ rowoff,
                                             int* __restrict__ col,
                                             float* __restrict__ dis,
                                             uint2* __restrict__ xd,
                                             int N, int E, int NB) {
  __shared__ int hist[512];
  __shared__ int loff[512];
  __shared__ int scan_s[256];
  int b = blockIdx.x;
  int tid = threadIdx.x;
  int ebase = bucketOff[b], eend = bucketOff[b + 1];
  int ecnt = eend - ebase;
  hist[tid] = 0; hist[tid + 256] = 0;
  __syncthreads();
  for (int i = tid; i < ecnt; i += 256)
    atomicAdd(&hist[ebuf[ebase + i] & 511u], 1);
  __syncthreads();
  int h0 = hist[2 * tid], h1 = hist[2 * tid + 1];
  int ts = h0 + h1;
  scan_s[tid] = ts;
  __syncthreads();
  for (int off = 1; off < 256; off <<= 1) {
    int t = (tid >= off) ? scan_s[tid - off] : 0;
    __syncthreads();
    scan_s[tid] += t;
    __syncthreads();
  }
  int excl = scan_s[tid] - ts;
  loff[2 * tid] = excl;
  loff[2 * tid + 1] = excl + h0;
  __syncthreads();
  int gbase = b * 512;
  for (int i = tid; i < 512; i += 256) {
    int node = gbase + i;
    if (node < N) {
      rowoff[node] = ebase + loff[i];
      float d = rsqrtf((float)hist[i] + 1.0f);
      dis[node] = d;
      xd[node] = make_uint2(pack2(d * x[node * 3 + 0], d * x[node * 3 + 1]),
                            pack2(d * x[node * 3 + 2], 0.f));
    }
  }
  if (b == NB - 1 && tid == 0) rowoff[N] = E;
  __syncthreads();
  for (int i = tid; i < ecnt; i += 256) {
    u32 ed = ebuf[ebase + i];
    int p = atomicAdd(&loff[ed & 511u], 1);
    col[ebase + p] = (int)(ed >> 9);
  }
}

// ---------------- L1 fused gather/gemm1 (bf16 xd) ----------------

__global__ void k_l1(const uint2* __restrict__ xd, const int* __restrict__ rowoff,
                     const int* __restrict__ col, const float* __restrict__ dis,
                     const float* __restrict__ W, const float* __restrict__ b,
                     u16* __restrict__ z, int n) {
  int wid = (blockIdx.x * blockDim.x + threadIdx.x) >> 6;
  int lane = threadIdx.x & 63;
  if (wid >= n) return;
  float a0 = 0.f, a1 = 0.f, a2 = 0.f;
  int beg = rowoff[wid], end = rowoff[wid + 1];
  for (int e = beg + lane; e < end; e += 64) {
    uint2 v = xd[col[e]];
    a0 += b2f_lo(v.x); a1 += b2f_hi(v.x); a2 += b2f_lo(v.y);
  }
#pragma unroll
  for (int off = 32; off; off >>= 1) {
    a0 += __shfl_xor(a0, off); a1 += __shfl_xor(a1, off); a2 += __shfl_xor(a2, off);
  }
  float di = dis[wid];
  uint2 sv = xd[wid];   // = di * x[wid] : the self term u_i
  a0 = di * (a0 + b2f_lo(sv.x));
  a1 = di * (a1 + b2f_hi(sv.x));
  a2 = di * (a2 + b2f_lo(sv.y));
  float zv = a0 * W[lane] + a1 * W[64 + lane] + a2 * W[128 + lane] + b[lane];
  z[(size_t)wid * 64 + lane] = f2b(zv);
}

// ---------------- aggregations with fused BN/lrelu/dis (packed math) ----------------

// D=64: wave/node, 8 sub-waves of 8 lanes (uint4 = 8 feats each), 4-deep pipeline
// -> 32 edges in flight per wave
__global__ void k_agg64(const u16* __restrict__ z, const int* __restrict__ rowoff,
                        const int* __restrict__ col, const float* __restrict__ dis,
                        const float* __restrict__ scaleF, const float* __restrict__ shiftF,
                        u16* __restrict__ a, int n) {
  int wid = (blockIdx.x * blockDim.x + threadIdx.x) >> 6;
  int lane = threadIdx.x & 63;
  if (wid >= n) return;
  int sub = lane >> 3, c = lane & 7;
  const uint4* z4 = (const uint4*)z;
  f32x2 sc2[4], sh2[4];
#pragma unroll
  for (int p = 0; p < 4; ++p) {
    sc2[p] = *(const f32x2*)&scaleF[c * 8 + p * 2];
    sh2[p] = *(const f32x2*)&shiftF[c * 8 + p * 2];
  }
  f32x2 acc[4] = {{0.f, 0.f}, {0.f, 0.f}, {0.f, 0.f}, {0.f, 0.f}};
  int beg = rowoff[wid], end = rowoff[wid + 1];
  int e = beg + sub;
  int j[4]; float d[4];
#pragma unroll
  for (int t = 0; t < 4; ++t) {
    int ee = e + 8 * t;
    j[t] = (ee < end) ? col[ee] : -1;
  }
#pragma unroll
  for (int t = 0; t < 4; ++t) d[t] = (j[t] >= 0) ? dis[j[t]] : 0.f;
  while (j[0] >= 0) {
    int en = e + 32;
    int nj[4]; float nd[4];
    bool more = (j[3] >= 0);
#pragma unroll
    for (int t = 0; t < 4; ++t) {
      int ee = en + 8 * t;
      nj[t] = (more && ee < end) ? col[ee] : -1;
    }
#pragma unroll
    for (int t = 0; t < 4; ++t) nd[t] = (nj[t] >= 0) ? dis[nj[t]] : 0.f;
    bn8_acc(z4[(size_t)j[0] * 8 + c], sc2, sh2, d[0], acc);
    if (j[1] >= 0) bn8_acc(z4[(size_t)j[1] * 8 + c], sc2, sh2, d[1], acc);
    if (j[2] >= 0) bn8_acc(z4[(size_t)j[2] * 8 + c], sc2, sh2, d[2], acc);
    if (j[3] >= 0) bn8_acc(z4[(size_t)j[3] * 8 + c], sc2, sh2, d[3], acc);
    e = en;
#pragma unroll
    for (int t = 0; t < 4; ++t) { j[t] = nj[t]; d[t] = nd[t]; }
  }
  float* af = (float*)acc;
#pragma unroll
  for (int k = 0; k < 8; ++k) {
    af[k] += __shfl_xor(af[k], 8);
    af[k] += __shfl_xor(af[k], 16);
    af[k] += __shfl_xor(af[k], 32);
  }
  if (sub == 0) {
    float dw = dis[wid];
    bn8_acc(z4[(size_t)wid * 8 + c], sc2, sh2, dw, acc);
    uint4 r;
    r.x = pack2(dw * af[0], dw * af[1]);
    r.y = pack2(dw * af[2], dw * af[3]);
    r.z = pack2(dw * af[4], dw * af[5]);
    r.w = pack2(dw * af[6], dw * af[7]);
    ((uint4*)a)[(size_t)wid * 8 + c] = r;
  }
}

// D=256: wave/node, 2 sub-waves of 32 lanes (uint4 = 8 feats each)  [floor config]
__global__ void k_agg256(const u16* __restrict__ z, const int* __restrict__ rowoff,
                         const int* __restrict__ col, const float* __restrict__ dis,
                         const float* __restrict__ scaleF, const float* __restrict__ shiftF,
                         u16* __restrict__ a, int n) {
  int wid = (blockIdx.x * blockDim.x + threadIdx.x) >> 6;
  int lane = threadIdx.x & 63;
  if (wid >= n) return;
  int sub = lane >> 5, c = lane & 31;
  const uint4* z4 = (const uint4*)z;
  f32x2 sc2[4], sh2[4];
#pragma unroll
  for (int p = 0; p < 4; ++p) {
    sc2[p] = *(const f32x2*)&scaleF[c * 8 + p * 2];
    sh2[p] = *(const f32x2*)&shiftF[c * 8 + p * 2];
  }
  f32x2 acc[4] = {{0.f, 0.f}, {0.f, 0.f}, {0.f, 0.f}, {0.f, 0.f}};
  int beg = rowoff[wid], end = rowoff[wid + 1];
  int e = beg + sub;
  int j1 = (e < end) ? col[e] : -1;
  int j2 = (e + 2 < end) ? col[e + 2] : -1;
  float d1 = (j1 >= 0) ? dis[j1] : 0.f;
  float d2 = (j2 >= 0) ? dis[j2] : 0.f;
  while (j1 >= 0) {
    int en = e + 4;
    int nj1 = -1, nj2 = -1;
    if (j2 >= 0) {
      if (en < end) nj1 = col[en];
      if (en + 2 < end) nj2 = col[en + 2];
    }
    float nd1 = (nj1 >= 0) ? dis[nj1] : 0.f;
    float nd2 = (nj2 >= 0) ? dis[nj2] : 0.f;
    bn8_acc(z4[(size_t)j1 * 32 + c], sc2, sh2, d1, acc);
    if (j2 >= 0) bn8_acc(z4[(size_t)j2 * 32 + c], sc2, sh2, d2, acc);
    e = en; j1 = nj1; j2 = nj2; d1 = nd1; d2 = nd2;
  }
  float* af = (float*)acc;
#pragma unroll
  for (int k = 0; k < 8; ++k) af[k] += __shfl_xor(af[k], 32);
  if (sub == 0) {
    float dw = dis[wid];
    bn8_acc(z4[(size_t)wid * 32 + c], sc2, sh2, dw, acc);
    uint4 r;
    r.x = pack2(dw * af[0], dw * af[1]);
    r.y = pack2(dw * af[2], dw * af[3]);
    r.z = pack2(dw * af[4], dw * af[5]);
    r.w = pack2(dw * af[6], dw * af[7]);
    ((uint4*)a)[(size_t)wid * 32 + c] = r;
  }
}

// ---------------- weight transpose (all 4 MFMA layers; also zeroes bucketCnt) ----------------

__global__ void k_wt_all(const float* __restrict__ W2, const float* __restrict__ W3,
                         const float* __restrict__ W4, const float* __restrict__ W5,
                         u16* __restrict__ WT, int* __restrict__ bucketCnt) {
  int i = blockIdx.x * blockDim.x + threadIdx.x;
  if (blockIdx.x == 0) bucketCnt[threadIdx.x] = 0;
  const float* W; int K, Fo, base;
  if (i < 4096)        { W = W2; K = 64;  Fo = 64;  base = 0; }
  else if (i < 20480)  { W = W3; K = 64;  Fo = 256; base = 4096; }
  else if (i < 86016)  { W = W4; K = 256; Fo = 256; base = 20480; }
  else if (i < 217088) { W = W5; K = 256; Fo = 512; base = 86016; }
  else return;
  int idx = i - base;
  int f = idx / K, k = idx - f * K;
  WT[i] = f2b(W[(size_t)k * Fo + f]);
}

// ---------------- MFMA GEMM: global_load_lds + XOR-swizzled LDS, fused stats ----------------

__global__ __launch_bounds__(256) void k_gemm(const u16* __restrict__ A,
                                              const u16* __restrict__ WT,
                                              const float* __restrict__ bias,
                                              u16* __restrict__ C,
                                              float* __restrict__ psum,
                                              float* __restrict__ psq,
                                              int n, int K, int Fo, int nby) {
  __shared__ u16 As[128 * 64];   // linear, XOR-swizzled: byte ^= (row&7)<<4
  __shared__ u16 Bs[128 * 64];
  int tid = threadIdx.x;
  int nwg = gridDim.x;
  int bid = blockIdx.x;
  int q = nwg >> 3, rr = nwg & 7;
  int xcd = bid & 7, pos = bid >> 3;
  int wgid = (xcd < rr ? xcd * (q + 1) : rr * (q + 1) + (xcd - rr) * q) + pos;
  int bx = wgid / nby, by = wgid - bx * nby;
  int bm0 = bx * 128, bn0 = by * 128;
  int lane = tid & 63, wv = tid >> 6;
  int wm = wv >> 1, wn = wv & 1;
  int fr = lane & 15, fg = lane >> 4;
  int srow = lane >> 3;                 // 0..7
  int cb = (lane & 7) ^ srow;           // 0..7
  f32x4 acc[4][4];
#pragma unroll
  for (int i = 0; i < 4; ++i)
#pragma unroll
    for (int j = 0; j < 4; ++j) acc[i][j] = (f32x4)0.0f;

  for (int kt = 0; kt < K; kt += 64) {
#pragma unroll
    for (int i = 0; i < 4; ++i) {
      int rb = 8 * (4 * wv + i);
      const u16* ga = &A[(size_t)(bm0 + rb + srow) * K + kt + cb * 8];
      gload16(ga, &As[rb * 64 + lane * 8]);
      const u16* gb = &WT[(size_t)(bn0 + rb + srow) * K + kt + cb * 8];
      gload16(gb, &Bs[rb * 64 + lane * 8]);
    }
    __syncthreads();
#pragma unroll
    for (int ks = 0; ks < 2; ++ks) {
      int k0 = ks * 32 + fg * 8;
      bf16x8 af[4], bf[4];
#pragma unroll
      for (int mi = 0; mi < 4; ++mi) {
        int row = wm * 64 + mi * 16 + fr;
        int byt = (row * 128 + k0 * 2) ^ ((row & 7) << 4);
        af[mi] = *(const bf16x8*)((const char*)As + byt);
      }
#pragma unroll
      for (int ni = 0; ni < 4; ++ni) {
        int row = wn * 64 + ni * 16 + fr;
        int byt = (row * 128 + k0 * 2) ^ ((row & 7) << 4);
        bf[ni] = *(const bf16x8*)((const char*)Bs + byt);
      }
#pragma unroll
      for (int mi = 0; mi < 4; ++mi)
#pragma unroll
        for (int ni = 0; ni < 4; ++ni)
          acc[mi][ni] = __builtin_amdgcn_mfma_f32_16x16x32_bf16(af[mi], bf[ni], acc[mi][ni], 0, 0, 0);
    }
    __syncthreads();
  }
  float* s2 = (float*)&As[0];
#pragma unroll
  for (int ni = 0; ni < 4; ++ni) {
    int gc = bn0 + wn * 64 + ni * 16 + fr;
    float ps = 0.f, pq = 0.f;
    if (gc < Fo) {
      float bv = bias[gc];
#pragma unroll
      for (int mi = 0; mi < 4; ++mi) {
#pragma unroll
        for (int rg = 0; rg < 4; ++rg) {
          int gr = bm0 + wm * 64 + mi * 16 + fg * 4 + rg;
          if (gr < n) {
            float v = acc[mi][ni][rg] + bv;
            C[(size_t)gr * Fo + gc] = f2b(v);
            ps += v; pq += v * v;
          }
        }
      }
    }
    ps += __shfl_xor(ps, 16); ps += __shfl_xor(ps, 32);
    pq += __shfl_xor(pq, 16); pq += __shfl_xor(pq, 32);
    if (fg == 0 && gc < Fo) {
      int cl = wn * 64 + ni * 16 + fr;
      s2[wm * 128 + cl] = ps;
      s2[256 + wm * 128 + cl] = pq;
    }
  }
  __syncthreads();
  if (tid < 128) {
    int gc = bn0 + tid;
    if (gc < Fo) {
      psum[(size_t)gc * LDP + bx] = s2[tid] + s2[128 + tid];
      psq[(size_t)gc * LDP + bx] = s2[256 + tid] + s2[384 + tid];
    }
  }
}

// ---------------- BN stats ----------------

__global__ void k_colred(const u16* __restrict__ z, int Fo, int n, int rowsPerChunk,
                         float* __restrict__ psum, float* __restrict__ psq) {
  int fl = threadIdx.x & 63;
  int rg = threadIdx.x >> 6;
  int f = blockIdx.y * 64 + fl;
  int r0 = blockIdx.x * rowsPerChunk;
  int r1 = min(n, r0 + rowsPerChunk);
  float s = 0.f, sq = 0.f;
  for (int r = r0 + rg; r < r1; r += 4) {
    float v = b2f(z[(size_t)r * Fo + f]);
    s += v;
    sq += v * v;
  }
  __shared__ float ls[4][64], lq[4][64];
  ls[rg][fl] = s; lq[rg][fl] = sq;
  __syncthreads();
  if (rg == 0) {
    psum[(size_t)f * LDP + blockIdx.x] = ls[0][fl] + ls[1][fl] + ls[2][fl] + ls[3][fl];
    psq[(size_t)f * LDP + blockIdx.x] = lq[0][fl] + lq[1][fl] + lq[2][fl] + lq[3][fl];
  }
}

__global__ void k_bnparams(const float* __restrict__ psum, const float* __restrict__ psq,
                           int Fo, int nChunks, int n,
                           const float* __restrict__ g, const float* __restrict__ bt,
                           float* __restrict__ scaleF, float* __restrict__ shiftF) {
  int f = blockIdx.x * 4 + (threadIdx.x >> 6);
  int lane = threadIdx.x & 63;
  if (f >= Fo) return;
  float s = 0.f, sq = 0.f;
  const float* ps = &psum[(size_t)f * LDP];
  const float* pq = &psq[(size_t)f * LDP];
  for (int c = lane; c < nChunks; c += 64) { s += ps[c]; sq += pq[c]; }
#pragma unroll
  for (int off = 32; off; off >>= 1) {
    s += __shfl_xor(s, off);
    sq += __shfl_xor(sq, off);
  }
  if (lane == 0) {
    float inv = 1.0f / (float)n;
    float mu = s * inv;
    float var = sq * inv - mu * mu;
    float rs = rsqrtf(var + EPS_BN) * g[f];
    scaleF[f] = rs;
    shiftF[f] = bt[f] - mu * rs;
  }
}

// ---------------- final layer ----------------

__global__ void k_dot512(const u16* __restrict__ z, const float* __restrict__ scaleF,
                         const float* __restrict__ shiftF, const float* __restrict__ w6,
                         const float* __restrict__ dis, float* __restrict__ v, int n) {
  __shared__ float ws[512], scs[512], shs[512];
  int tid = threadIdx.x;
  for (int i = tid; i < 512; i += 256) { ws[i] = w6[i]; scs[i] = scaleF[i]; shs[i] = shiftF[i]; }
  __syncthreads();
  int lane = tid % 64, wv = tid / 64;
  int node = blockIdx.x * 4 + wv;
  if (node >= n) return;
  uint4 vz = *(const uint4*)&z[(size_t)node * 512 + lane * 8];
  float f[8];
  unpack8(vz, f);
  int f0 = lane * 8;
  float s = 0.f;
#pragma unroll
  for (int k = 0; k < 8; ++k) {
    float a = f[k] * scs[f0 + k] + shs[f0 + k];
    a = (a > 0.f) ? a : NEG * a;
    s += a * ws[f0 + k];
  }
#pragma unroll
  for (int off = 32; off > 0; off >>= 1) s += __shfl_down(s, off);
  if (lane == 0) v[node] = dis[node] * s;
}

__global__ void k_final(const float* __restrict__ v, const int* __restrict__ rowoff,
                        const int* __restrict__ col, const float* __restrict__ dis,
                        const float* __restrict__ b6, float* __restrict__ out, int n) {
  int wid = (blockIdx.x * blockDim.x + threadIdx.x) >> 6;
  int lane = threadIdx.x & 63;
  if (wid >= n) return;
  float acc = 0.f;
  int beg = rowoff[wid], end = rowoff[wid + 1];
  for (int e = beg + lane; e < end; e += 64) acc += v[col[e]];
#pragma unroll
  for (int off = 32; off; off >>= 1) acc += __shfl_xor(acc, off);
  if (lane == 0) {
    float zz = dis[wid] * (acc + v[wid]) + b6[0];
    out[wid] = 1.0f / (1.0f + expf(-zz));
  }
}

// ---------------- driver ----------------

extern "C" void kernel_launch(void* const* d_in, const int* in_sizes, int n_in,
                              void* d_out, int out_size, void* d_ws, size_t ws_size,
                              hipStream_t stream) {
  const float* x = (const float*)d_in[0];
  const int* ei = (const int*)d_in[1];
  const int N = in_sizes[0] / 3;
  const int E = in_sizes[1] / 2;
  const int* srcIdx = ei;
  const int* dstIdx = ei + E;

  const float* W[6]; const float* b[6];
  for (int i = 0; i < 6; ++i) { W[i] = (const float*)d_in[2 + 2 * i]; b[i] = (const float*)d_in[3 + 2 * i]; }
  const float* g[5]; const float* bt[5];
  for (int i = 0; i < 5; ++i) { g[i] = (const float*)d_in[14 + 2 * i]; bt[i] = (const float*)d_in[15 + 2 * i]; }

  char* wsB = (char*)d_ws;
  size_t off = 0;
  auto alloc = [&](size_t bytes) -> void* {
    void* p = wsB + off;
    off = (off + bytes + 255) & ~(size_t)255;
    return p;
  };

  const int NB = cdiv(N, 512);
  int* rowoff = (int*)alloc((size_t)(N + 1) * 4);
  int* col = (int*)alloc((size_t)E * 4);
  float* dis = (float*)alloc((size_t)N * 4);
  float* vbuf = (float*)alloc((size_t)N * 4);
  float* scaleF = (float*)alloc(512 * 4);
  float* shiftF = (float*)alloc(512 * 4);
  uint2* xd = (uint2*)alloc((size_t)N * 8);
  u16* WTb = (u16*)alloc((size_t)217088 * 2);
  int* bucketCnt = (int*)alloc(256 * 4);
  int* bucketOff = (int*)alloc(257 * 4);
  int* bucketCur = (int*)alloc(256 * 4);
  const int nbx = cdiv(N, 128);
  float* psum = (float*)alloc((size_t)512 * LDP * 4);
  float* psq = (float*)alloc((size_t)512 * LDP * 4);
  u16* Zb = (u16*)alloc((size_t)N * 512 * 2);
  u16* Ab = (u16*)alloc((size_t)(N + 128) * 256 * 2);  // +128 rows slack for gload_lds
  u32* ebuf = (u32*)Ab;   // alias: only used during CSR build

  // WT offsets (elements): W2:0, W3:4096, W4:20480, W5:86016
  const int wtOff[5] = {0, 0, 4096, 20480, 86016};
  k_wt_all<<<cdiv(217088, 256), 256, 0, stream>>>(W[1], W[2], W[3], W[4], WTb, bucketCnt);

  // ---- CSR build (+dis, +xd) ----
  const int EB = cdiv(E, 4096);
  k_bcount<<<EB, 256, 0, stream>>>(dstIdx, bucketCnt, E);
  k_bscan<<<1, 256, 0, stream>>>(bucketCnt, bucketOff, bucketCur, NB, E);
  k_bucket<<<EB, 256, 0, stream>>>(srcIdx, dstIdx, bucketOff, bucketCur, ebuf, E);
  k_csr<<<NB, 256, 0, stream>>>(ebuf, bucketOff, x, rowoff, col, dis, xd, N, E, NB);

  auto gemm = [&](const u16* Ain, int layer, int K, int Fo, u16* Cout) {
    int nby = cdiv(Fo, 128);
    k_gemm<<<nbx * nby, 256, 0, stream>>>(Ain, WTb + wtOff[layer], b[layer], Cout,
                                          psum, psq, N, K, Fo, nby);
    k_bnparams<<<cdiv(Fo, 4), 256, 0, stream>>>(psum, psq, Fo, nbx, N,
                                                g[layer], bt[layer], scaleF, shiftF);
  };

  const int waveGrid = cdiv(N * 64, 256);

  // ---- L1 (fully fused) ----
  k_l1<<<waveGrid, 256, 0, stream>>>(xd, rowoff, col, dis, W[0], b[0], Zb, N);
  {
    const int rowsPerChunk = 2048;
    const int nChunks = cdiv(N, rowsPerChunk);
    dim3 grid(nChunks, 1);
    k_colred<<<grid, 256, 0, stream>>>(Zb, 64, N, rowsPerChunk, psum, psq);
    k_bnparams<<<cdiv(64, 4), 256, 0, stream>>>(psum, psq, 64, nChunks, N, g[0], bt[0], scaleF, shiftF);
  }

  // ---- L2 (agg reads raw z + BN params) ----
  k_agg64<<<waveGrid, 256, 0, stream>>>(Zb, rowoff, col, dis, scaleF, shiftF, Ab, N);
  gemm(Ab, 1, 64, 64, Zb);

  // ---- L3 ----
  k_agg64<<<waveGrid, 256, 0, stream>>>(Zb, rowoff, col, dis, scaleF, shiftF, Ab, N);
  gemm(Ab, 2, 64, 256, Zb);

  // ---- L4 ----
  k_agg256<<<waveGrid, 256, 0, stream>>>(Zb, rowoff, col, dis, scaleF, shiftF, Ab, N);
  gemm(Ab, 3, 256, 256, Zb);

  // ---- L5 ----
  k_agg256<<<waveGrid, 256, 0, stream>>>(Zb, rowoff, col, dis, scaleF, shiftF, Ab, N);
  gemm(Ab, 4, 256, 512, Zb);

  // ---- L6 ----
  k_dot512<<<cdiv(N, 4), 256, 0, stream>>>(Zb, scaleF, shiftF, W[5], dis, vbuf, N);
  k_final<<<waveGrid, 256, 0, stream>>>(vbuf, rowoff, col, dis, b[5], (float*)d_out, N);
}

// Round 13
// 1159.837 us; speedup vs baseline: 1.0248x; 1.0248x over previous
//
#include <hip/hip_runtime.h>
#include <math.h>

typedef unsigned short u16;
typedef unsigned int u32;
typedef __attribute__((ext_vector_type(8))) short bf16x8;
typedef __attribute__((ext_vector_type(4))) float f32x4;
typedef __attribute__((ext_vector_type(2))) float f32x2;

constexpr float EPS_BN = 1e-5f;
constexpr float NEG = 0.1f;
constexpr int LDP = 800;   // leading dim of psum/psq: [feature][chunk<=LDP]

static inline int cdiv(int a, int b) { return (a + b - 1) / b; }

// ---------------- bf16 helpers ----------------

__device__ __forceinline__ float b2f_lo(u32 v) { return __uint_as_float(v << 16); }
__device__ __forceinline__ float b2f_hi(u32 v) { return __uint_as_float(v & 0xFFFF0000u); }
__device__ __forceinline__ float b2f(u16 v) { return __uint_as_float(((u32)v) << 16); }
__device__ __forceinline__ u16 f2b(float f) {
  u32 u = __float_as_uint(f);
  u32 r = u + 0x7FFFu + ((u >> 16) & 1u);
  return (u16)(r >> 16);
}
__device__ __forceinline__ u32 pack2(float a, float b) {
  return (u32)f2b(a) | ((u32)f2b(b) << 16);
}
__device__ __forceinline__ void unpack8(uint4 v, float* o) {
  o[0] = b2f_lo(v.x); o[1] = b2f_hi(v.x);
  o[2] = b2f_lo(v.y); o[3] = b2f_hi(v.y);
  o[4] = b2f_lo(v.z); o[5] = b2f_hi(v.z);
  o[6] = b2f_lo(v.w); o[7] = b2f_hi(v.w);
}

__device__ __forceinline__ void gload16(const void* g, void* l) {
  __builtin_amdgcn_global_load_lds(
      (const __attribute__((address_space(1))) u32*)g,
      (__attribute__((address_space(3))) u32*)l, 16, 0, 0);
}

// packed BN+lrelu+accumulate: acc[p] += d * lrelu(z*sc+sh), 8 feats (4 pairs)
__device__ __forceinline__ void bn8_acc(uint4 v, const f32x2* sc2, const f32x2* sh2,
                                        float d, f32x2* acc) {
  const f32x2 dd = {d, d};
  const f32x2 c01 = {NEG, NEG};
  const u32* w = &v.x;
#pragma unroll
  for (int p = 0; p < 4; ++p) {
    f32x2 z = {b2f_lo(w[p]), b2f_hi(w[p])};
    f32x2 t = z * sc2[p] + sh2[p];                       // v_pk_fma
    f32x2 q = __builtin_elementwise_max(t, t * c01);     // v_pk_mul + v_pk_max
    acc[p] = dd * q + acc[p];                            // v_pk_fma
  }
}

// ---------------- CSR build (bucketed, packed ebuf) ----------------

__global__ __launch_bounds__(256) void k_bcount(const int* __restrict__ dst,
                                                int* __restrict__ bucketCnt, int E) {
  __shared__ int hist[256];
  int tid = threadIdx.x;
  hist[tid] = 0;
  __syncthreads();
  int e0 = blockIdx.x * 4096;
#pragma unroll
  for (int i = 0; i < 16; ++i) {
    int e = e0 + i * 256 + tid;
    if (e < E) atomicAdd(&hist[dst[e] >> 9], 1);
  }
  __syncthreads();
  int h = hist[tid];
  if (h > 0) atomicAdd(&bucketCnt[tid], h);
}

__global__ void k_bscan(const int* __restrict__ bucketCnt, int* __restrict__ bucketOff,
                        int* __restrict__ bucketCur, int NB, int E) {
  __shared__ int s[256];
  int tid = threadIdx.x;
  int v = (tid < NB) ? bucketCnt[tid] : 0;
  s[tid] = v;
  __syncthreads();
  for (int off = 1; off < 256; off <<= 1) {
    int t = (tid >= off) ? s[tid - off] : 0;
    __syncthreads();
    s[tid] += t;
    __syncthreads();
  }
  if (tid < NB) bucketOff[tid] = s[tid] - v;
  if (tid == NB) bucketOff[NB] = E;
  if (tid < NB) bucketCur[tid] = 0;
}

__global__ __launch_bounds__(256) void k_bucket(const int* __restrict__ src,
                                                const int* __restrict__ dst,
                                                const int* __restrict__ bucketOff,
                                                int* __restrict__ bucketCur,
                                                u32* __restrict__ ebuf, int E) {
  __shared__ int hist[256];
  __shared__ int base[256];
  __shared__ int lcur[256];
  int tid = threadIdx.x;
  hist[tid] = 0; lcur[tid] = 0;
  __syncthreads();
  int e0 = blockIdx.x * 4096;
  int ss[16], dd[16];
#pragma unroll
  for (int i = 0; i < 16; ++i) {
    int e = e0 + i * 256 + tid;
    if (e < E) {
      ss[i] = src[e]; dd[i] = dst[e];
      atomicAdd(&hist[dd[i] >> 9], 1);
    } else dd[i] = -1;
  }
  __syncthreads();
  int h = hist[tid];
  if (h > 0) base[tid] = bucketOff[tid] + atomicAdd(&bucketCur[tid], h);
  __syncthreads();
#pragma unroll
  for (int i = 0; i < 16; ++i) {
    if (dd[i] >= 0) {
      int bk = dd[i] >> 9;
      int p = atomicAdd(&lcur[bk], 1);
      ebuf[base[bk] + p] = ((u32)ss[i] << 9) | ((u32)dd[i] & 511u);
    }
  }
}

// per-bucket CSR finalize + dis + xd(bf16) = dis*x
__global__ __launch_bounds__(256) void k_csr(const u32* __restrict__ ebuf,
                                             const int* __restrict__ bucketOff,
                                             const float* __restrict__ x,
                                             int* __restrict__ rowoff,
                                             int* __restrict__ col,
                                             float* __restrict__ dis,
                                             uint2* __restrict__ xd,
                                             int N, int E, int NB) {
  __shared__ int hist[512];
  __shared__ int loff[512];
  __shared__ int scan_s[256];
  int b = blockIdx.x;
  int tid = threadIdx.x;
  int ebase = bucketOff[b], eend = bucketOff[b + 1];
  int ecnt = eend - ebase;
  hist[tid] = 0; hist[tid + 256] = 0;
  __syncthreads();
  for (int i = tid; i < ecnt; i += 256)
    atomicAdd(&hist[ebuf[ebase + i] & 511u], 1);
  __syncthreads();
  int h0 = hist[2 * tid], h1 = hist[2 * tid + 1];
  int ts = h0 + h1;
  scan_s[tid] = ts;
  __syncthreads();
  for (int off = 1; off < 256; off <<= 1) {
    int t = (tid >= off) ? scan_s[tid - off] : 0;
    __syncthreads();
    scan_s[tid] += t;
    __syncthreads();
  }
  int excl = scan_s[tid] - ts;
  loff[2 * tid] = excl;
  loff[2 * tid + 1] = excl + h0;
  __syncthreads();
  int gbase = b * 512;
  for (int i = tid; i < 512; i += 256) {
    int node = gbase + i;
    if (node < N) {
      rowoff[node] = ebase + loff[i];
      float d = rsqrtf((float)hist[i] + 1.0f);
      dis[node] = d;
      xd[node] = make_uint2(pack2(d * x[node * 3 + 0], d * x[node * 3 + 1]),
                            pack2(d * x[node * 3 + 2], 0.f));
    }
  }
  if (b == NB - 1 && tid == 0) rowoff[N] = E;
  __syncthreads();
  for (int i = tid; i < ecnt; i += 256) {
    u32 ed = ebuf[ebase + i];
    int p = atomicAdd(&loff[ed & 511u], 1);
    col[ebase + p] = (int)(ed >> 9);
  }
}

// ---------------- L1 fused gather/gemm1 (bf16 xd) ----------------

__global__ void k_l1(const uint2* __restrict__ xd, const int* __restrict__ rowoff,
                     const int* __restrict__ col, const float* __restrict__ dis,
                     const float* __restrict__ W, const float* __restrict__ b,
                     u16* __restrict__ z, int n) {
  int wid = (blockIdx.x * blockDim.x + threadIdx.x) >> 6;
  int lane = threadIdx.x & 63;
  if (wid >= n) return;
  float a0 = 0.f, a1 = 0.f, a2 = 0.f;
  int beg = rowoff[wid], end = rowoff[wid + 1];
  for (int e = beg + lane; e < end; e += 64) {
    uint2 v = xd[col[e]];
    a0 += b2f_lo(v.x); a1 += b2f_hi(v.x); a2 += b2f_lo(v.y);
  }
#pragma unroll
  for (int off = 32; off; off >>= 1) {
    a0 += __shfl_xor(a0, off); a1 += __shfl_xor(a1, off); a2 += __shfl_xor(a2, off);
  }
  float di = dis[wid];
  uint2 sv = xd[wid];   // = di * x[wid] : the self term u_i
  a0 = di * (a0 + b2f_lo(sv.x));
  a1 = di * (a1 + b2f_hi(sv.x));
  a2 = di * (a2 + b2f_lo(sv.y));
  float zv = a0 * W[lane] + a1 * W[64 + lane] + a2 * W[128 + lane] + b[lane];
  z[(size_t)wid * 64 + lane] = f2b(zv);
}

// ---------------- aggregations with fused BN/lrelu/dis (packed math) ----------------

// D=64: wave/node, 8 sub-waves of 8 lanes (uint4 = 8 feats each), 16 edges in flight
__global__ void k_agg64(const u16* __restrict__ z, const int* __restrict__ rowoff,
                        const int* __restrict__ col, const float* __restrict__ dis,
                        const float* __restrict__ scaleF, const float* __restrict__ shiftF,
                        u16* __restrict__ a, int n) {
  int wid = (blockIdx.x * blockDim.x + threadIdx.x) >> 6;
  int lane = threadIdx.x & 63;
  if (wid >= n) return;
  int sub = lane >> 3, c = lane & 7;
  const uint4* z4 = (const uint4*)z;
  f32x2 sc2[4], sh2[4];
#pragma unroll
  for (int p = 0; p < 4; ++p) {
    sc2[p] = *(const f32x2*)&scaleF[c * 8 + p * 2];
    sh2[p] = *(const f32x2*)&shiftF[c * 8 + p * 2];
  }
  f32x2 acc[4] = {{0.f, 0.f}, {0.f, 0.f}, {0.f, 0.f}, {0.f, 0.f}};
  int beg = rowoff[wid], end = rowoff[wid + 1];
  int e = beg + sub;
  int j1 = (e < end) ? col[e] : -1;
  int j2 = (e + 8 < end) ? col[e + 8] : -1;
  float d1 = (j1 >= 0) ? dis[j1] : 0.f;
  float d2 = (j2 >= 0) ? dis[j2] : 0.f;
  while (j1 >= 0) {
    int en = e + 16;
    int nj1 = -1, nj2 = -1;
    if (j2 >= 0) {
      if (en < end) nj1 = col[en];
      if (en + 8 < end) nj2 = col[en + 8];
    }
    float nd1 = (nj1 >= 0) ? dis[nj1] : 0.f;
    float nd2 = (nj2 >= 0) ? dis[nj2] : 0.f;
    bn8_acc(z4[(size_t)j1 * 8 + c], sc2, sh2, d1, acc);
    if (j2 >= 0) bn8_acc(z4[(size_t)j2 * 8 + c], sc2, sh2, d2, acc);
    e = en; j1 = nj1; j2 = nj2; d1 = nd1; d2 = nd2;
  }
  float* af = (float*)acc;
#pragma unroll
  for (int k = 0; k < 8; ++k) {
    af[k] += __shfl_xor(af[k], 8);
    af[k] += __shfl_xor(af[k], 16);
    af[k] += __shfl_xor(af[k], 32);
  }
  if (sub == 0) {
    float dw = dis[wid];
    bn8_acc(z4[(size_t)wid * 8 + c], sc2, sh2, dw, acc);
    uint4 r;
    r.x = pack2(dw * af[0], dw * af[1]);
    r.y = pack2(dw * af[2], dw * af[3]);
    r.z = pack2(dw * af[4], dw * af[5]);
    r.w = pack2(dw * af[6], dw * af[7]);
    ((uint4*)a)[(size_t)wid * 8 + c] = r;
  }
}

// D=256: wave/node, 2 sub-waves of 32 lanes (uint4 = 8 feats each)  [floor config]
__global__ void k_agg256(const u16* __restrict__ z, const int* __restrict__ rowoff,
                         const int* __restrict__ col, const float* __restrict__ dis,
                         const float* __restrict__ scaleF, const float* __restrict__ shiftF,
                         u16* __restrict__ a, int n) {
  int wid = (blockIdx.x * blockDim.x + threadIdx.x) >> 6;
  int lane = threadIdx.x & 63;
  if (wid >= n) return;
  int sub = lane >> 5, c = lane & 31;
  const uint4* z4 = (const uint4*)z;
  f32x2 sc2[4], sh2[4];
#pragma unroll
  for (int p = 0; p < 4; ++p) {
    sc2[p] = *(const f32x2*)&scaleF[c * 8 + p * 2];
    sh2[p] = *(const f32x2*)&shiftF[c * 8 + p * 2];
  }
  f32x2 acc[4] = {{0.f, 0.f}, {0.f, 0.f}, {0.f, 0.f}, {0.f, 0.f}};
  int beg = rowoff[wid], end = rowoff[wid + 1];
  int e = beg + sub;
  int j1 = (e < end) ? col[e] : -1;
  int j2 = (e + 2 < end) ? col[e + 2] : -1;
  float d1 = (j1 >= 0) ? dis[j1] : 0.f;
  float d2 = (j2 >= 0) ? dis[j2] : 0.f;
  while (j1 >= 0) {
    int en = e + 4;
    int nj1 = -1, nj2 = -1;
    if (j2 >= 0) {
      if (en < end) nj1 = col[en];
      if (en + 2 < end) nj2 = col[en + 2];
    }
    float nd1 = (nj1 >= 0) ? dis[nj1] : 0.f;
    float nd2 = (nj2 >= 0) ? dis[nj2] : 0.f;
    bn8_acc(z4[(size_t)j1 * 32 + c], sc2, sh2, d1, acc);
    if (j2 >= 0) bn8_acc(z4[(size_t)j2 * 32 + c], sc2, sh2, d2, acc);
    e = en; j1 = nj1; j2 = nj2; d1 = nd1; d2 = nd2;
  }
  float* af = (float*)acc;
#pragma unroll
  for (int k = 0; k < 8; ++k) af[k] += __shfl_xor(af[k], 32);
  if (sub == 0) {
    float dw = dis[wid];
    bn8_acc(z4[(size_t)wid * 32 + c], sc2, sh2, dw, acc);
    uint4 r;
    r.x = pack2(dw * af[0], dw * af[1]);
    r.y = pack2(dw * af[2], dw * af[3]);
    r.z = pack2(dw * af[4], dw * af[5]);
    r.w = pack2(dw * af[6], dw * af[7]);
    ((uint4*)a)[(size_t)wid * 32 + c] = r;
  }
}

// ---------------- weight transpose (all 4 MFMA layers; also zeroes bucketCnt) ----------------

__global__ void k_wt_all(const float* __restrict__ W2, const float* __restrict__ W3,
                         const float* __restrict__ W4, const float* __restrict__ W5,
                         u16* __restrict__ WT, int* __restrict__ bucketCnt) {
  int i = blockIdx.x * blockDim.x + threadIdx.x;
  if (blockIdx.x == 0) bucketCnt[threadIdx.x] = 0;
  const float* W; int K, Fo, base;
  if (i < 4096)        { W = W2; K = 64;  Fo = 64;  base = 0; }
  else if (i < 20480)  { W = W3; K = 64;  Fo = 256; base = 4096; }
  else if (i < 86016)  { W = W4; K = 256; Fo = 256; base = 20480; }
  else if (i < 217088) { W = W5; K = 256; Fo = 512; base = 86016; }
  else return;
  int idx = i - base;
  int f = idx / K, k = idx - f * K;
  WT[i] = f2b(W[(size_t)k * Fo + f]);
}

// ---------------- MFMA GEMM: global_load_lds + XOR-swizzled LDS, fused stats ----------------

__global__ __launch_bounds__(256) void k_gemm(const u16* __restrict__ A,
                                              const u16* __restrict__ WT,
                                              const float* __restrict__ bias,
                                              u16* __restrict__ C,
                                              float* __restrict__ psum,
                                              float* __restrict__ psq,
                                              int n, int K, int Fo, int nby) {
  __shared__ u16 As[128 * 64];   // linear, XOR-swizzled: byte ^= (row&7)<<4
  __shared__ u16 Bs[128 * 64];
  int tid = threadIdx.x;
  int nwg = gridDim.x;
  int bid = blockIdx.x;
  int q = nwg >> 3, rr = nwg & 7;
  int xcd = bid & 7, pos = bid >> 3;
  int wgid = (xcd < rr ? xcd * (q + 1) : rr * (q + 1) + (xcd - rr) * q) + pos;
  int bx = wgid / nby, by = wgid - bx * nby;
  int bm0 = bx * 128, bn0 = by * 128;
  int lane = tid & 63, wv = tid >> 6;
  int wm = wv >> 1, wn = wv & 1;
  int fr = lane & 15, fg = lane >> 4;
  int srow = lane >> 3;                 // 0..7
  int cb = (lane & 7) ^ srow;           // 0..7
  f32x4 acc[4][4];
#pragma unroll
  for (int i = 0; i < 4; ++i)
#pragma unroll
    for (int j = 0; j < 4; ++j) acc[i][j] = (f32x4)0.0f;

  for (int kt = 0; kt < K; kt += 64) {
#pragma unroll
    for (int i = 0; i < 4; ++i) {
      int rb = 8 * (4 * wv + i);
      const u16* ga = &A[(size_t)(bm0 + rb + srow) * K + kt + cb * 8];
      gload16(ga, &As[rb * 64 + lane * 8]);
      const u16* gb = &WT[(size_t)(bn0 + rb + srow) * K + kt + cb * 8];
      gload16(gb, &Bs[rb * 64 + lane * 8]);
    }
    __syncthreads();
#pragma unroll
    for (int ks = 0; ks < 2; ++ks) {
      int k0 = ks * 32 + fg * 8;
      bf16x8 af[4], bf[4];
#pragma unroll
      for (int mi = 0; mi < 4; ++mi) {
        int row = wm * 64 + mi * 16 + fr;
        int byt = (row * 128 + k0 * 2) ^ ((row & 7) << 4);
        af[mi] = *(const bf16x8*)((const char*)As + byt);
      }
#pragma unroll
      for (int ni = 0; ni < 4; ++ni) {
        int row = wn * 64 + ni * 16 + fr;
        int byt = (row * 128 + k0 * 2) ^ ((row & 7) << 4);
        bf[ni] = *(const bf16x8*)((const char*)Bs + byt);
      }
#pragma unroll
      for (int mi = 0; mi < 4; ++mi)
#pragma unroll
        for (int ni = 0; ni < 4; ++ni)
          acc[mi][ni] = __builtin_amdgcn_mfma_f32_16x16x32_bf16(af[mi], bf[ni], acc[mi][ni], 0, 0, 0);
    }
    __syncthreads();
  }
  float* s2 = (float*)&As[0];
#pragma unroll
  for (int ni = 0; ni < 4; ++ni) {
    int gc = bn0 + wn * 64 + ni * 16 + fr;
    float ps = 0.f, pq = 0.f;
    if (gc < Fo) {
      float bv = bias[gc];
#pragma unroll
      for (int mi = 0; mi < 4; ++mi) {
#pragma unroll
        for (int rg = 0; rg < 4; ++rg) {
          int gr = bm0 + wm * 64 + mi * 16 + fg * 4 + rg;
          if (gr < n) {
            float v = acc[mi][ni][rg] + bv;
            C[(size_t)gr * Fo + gc] = f2b(v);
            ps += v; pq += v * v;
          }
        }
      }
    }
    ps += __shfl_xor(ps, 16); ps += __shfl_xor(ps, 32);
    pq += __shfl_xor(pq, 16); pq += __shfl_xor(pq, 32);
    if (fg == 0 && gc < Fo) {
      int cl = wn * 64 + ni * 16 + fr;
      s2[wm * 128 + cl] = ps;
      s2[256 + wm * 128 + cl] = pq;
    }
  }
  __syncthreads();
  if (tid < 128) {
    int gc = bn0 + tid;
    if (gc < Fo) {
      psum[(size_t)gc * LDP + bx] = s2[tid] + s2[128 + tid];
      psq[(size_t)gc * LDP + bx] = s2[256 + tid] + s2[384 + tid];
    }
  }
}

// ---------------- BN stats ----------------

__global__ void k_colred(const u16* __restrict__ z, int Fo, int n, int rowsPerChunk,
                         float* __restrict__ psum, float* __restrict__ psq) {
  int fl = threadIdx.x & 63;
  int rg = threadIdx.x >> 6;
  int f = blockIdx.y * 64 + fl;
  int r0 = blockIdx.x * rowsPerChunk;
  int r1 = min(n, r0 + rowsPerChunk);
  float s = 0.f, sq = 0.f;
  for (int r = r0 + rg; r < r1; r += 4) {
    float v = b2f(z[(size_t)r * Fo + f]);
    s += v;
    sq += v * v;
  }
  __shared__ float ls[4][64], lq[4][64];
  ls[rg][fl] = s; lq[rg][fl] = sq;
  __syncthreads();
  if (rg == 0) {
    psum[(size_t)f * LDP + blockIdx.x] = ls[0][fl] + ls[1][fl] + ls[2][fl] + ls[3][fl];
    psq[(size_t)f * LDP + blockIdx.x] = lq[0][fl] + lq[1][fl] + lq[2][fl] + lq[3][fl];
  }
}

__global__ void k_bnparams(const float* __restrict__ psum, const float* __restrict__ psq,
                           int Fo, int nChunks, int n,
                           const float* __restrict__ g, const float* __restrict__ bt,
                           float* __restrict__ scaleF, float* __restrict__ shiftF) {
  int f = blockIdx.x * 4 + (threadIdx.x >> 6);
  int lane = threadIdx.x & 63;
  if (f >= Fo) return;
  float s = 0.f, sq = 0.f;
  const float* ps = &psum[(size_t)f * LDP];
  const float* pq = &psq[(size_t)f * LDP];
  for (int c = lane; c < nChunks; c += 64) { s += ps[c]; sq += pq[c]; }
#pragma unroll
  for (int off = 32; off; off >>= 1) {
    s += __shfl_xor(s, off);
    sq += __shfl_xor(sq, off);
  }
  if (lane == 0) {
    float inv = 1.0f / (float)n;
    float mu = s * inv;
    float var = sq * inv - mu * mu;
    float rs = rsqrtf(var + EPS_BN) * g[f];
    scaleF[f] = rs;
    shiftF[f] = bt[f] - mu * rs;
  }
}

// ---------------- final layer ----------------

__global__ void k_dot512(const u16* __restrict__ z, const float* __restrict__ scaleF,
                         const float* __restrict__ shiftF, const float* __restrict__ w6,
                         const float* __restrict__ dis, float* __restrict__ v, int n) {
  __shared__ float ws[512], scs[512], shs[512];
  int tid = threadIdx.x;
  for (int i = tid; i < 512; i += 256) { ws[i] = w6[i]; scs[i] = scaleF[i]; shs[i] = shiftF[i]; }
  __syncthreads();
  int lane = tid % 64, wv = tid / 64;
  int node = blockIdx.x * 4 + wv;
  if (node >= n) return;
  uint4 vz = *(const uint4*)&z[(size_t)node * 512 + lane * 8];
  float f[8];
  unpack8(vz, f);
  int f0 = lane * 8;
  float s = 0.f;
#pragma unroll
  for (int k = 0; k < 8; ++k) {
    float a = f[k] * scs[f0 + k] + shs[f0 + k];
    a = (a > 0.f) ? a : NEG * a;
    s += a * ws[f0 + k];
  }
#pragma unroll
  for (int off = 32; off > 0; off >>= 1) s += __shfl_down(s, off);
  if (lane == 0) v[node] = dis[node] * s;
}

__global__ void k_final(const float* __restrict__ v, const int* __restrict__ rowoff,
                        const int* __restrict__ col, const float* __restrict__ dis,
                        const float* __restrict__ b6, float* __restrict__ out, int n) {
  int wid = (blockIdx.x * blockDim.x + threadIdx.x) >> 6;
  int lane = threadIdx.x & 63;
  if (wid >= n) return;
  float acc = 0.f;
  int beg = rowoff[wid], end = rowoff[wid + 1];
  for (int e = beg + lane; e < end; e += 64) acc += v[col[e]];
#pragma unroll
  for (int off = 32; off; off >>= 1) acc += __shfl_xor(acc, off);
  if (lane == 0) {
    float zz = dis[wid] * (acc + v[wid]) + b6[0];
    out[wid] = 1.0f / (1.0f + expf(-zz));
  }
}

// ---------------- driver ----------------

extern "C" void kernel_launch(void* const* d_in, const int* in_sizes, int n_in,
                              void* d_out, int out_size, void* d_ws, size_t ws_size,
                              hipStream_t stream) {
  const float* x = (const float*)d_in[0];
  const int* ei = (const int*)d_in[1];
  const int N = in_sizes[0] / 3;
  const int E = in_sizes[1] / 2;
  const int* srcIdx = ei;
  const int* dstIdx = ei + E;

  const float* W[6]; const float* b[6];
  for (int i = 0; i < 6; ++i) { W[i] = (const float*)d_in[2 + 2 * i]; b[i] = (const float*)d_in[3 + 2 * i]; }
  const float* g[5]; const float* bt[5];
  for (int i = 0; i < 5; ++i) { g[i] = (const float*)d_in[14 + 2 * i]; bt[i] = (const float*)d_in[15 + 2 * i]; }

  char* wsB = (char*)d_ws;
  size_t off = 0;
  auto alloc = [&](size_t bytes) -> void* {
    void* p = wsB + off;
    off = (off + bytes + 255) & ~(size_t)255;
    return p;
  };

  const int NB = cdiv(N, 512);
  int* rowoff = (int*)alloc((size_t)(N + 1) * 4);
  int* col = (int*)alloc((size_t)E * 4);
  float* dis = (float*)alloc((size_t)N * 4);
  float* vbuf = (float*)alloc((size_t)N * 4);
  float* scaleF = (float*)alloc(512 * 4);
  float* shiftF = (float*)alloc(512 * 4);
  uint2* xd = (uint2*)alloc((size_t)N * 8);
  u16* WTb = (u16*)alloc((size_t)217088 * 2);
  int* bucketCnt = (int*)alloc(256 * 4);
  int* bucketOff = (int*)alloc(257 * 4);
  int* bucketCur = (int*)alloc(256 * 4);
  const int nbx = cdiv(N, 128);
  float* psum = (float*)alloc((size_t)512 * LDP * 4);
  float* psq = (float*)alloc((size_t)512 * LDP * 4);
  u16* Zb = (u16*)alloc((size_t)N * 512 * 2);
  u16* Ab = (u16*)alloc((size_t)(N + 128) * 256 * 2);  // +128 rows slack for gload_lds
  u32* ebuf = (u32*)Ab;   // alias: only used during CSR build

  // WT offsets (elements): W2:0, W3:4096, W4:20480, W5:86016
  const int wtOff[5] = {0, 0, 4096, 20480, 86016};
  k_wt_all<<<cdiv(217088, 256), 256, 0, stream>>>(W[1], W[2], W[3], W[4], WTb, bucketCnt);

  // ---- CSR build (+dis, +xd) ----
  const int EB = cdiv(E, 4096);
  k_bcount<<<EB, 256, 0, stream>>>(dstIdx, bucketCnt, E);
  k_bscan<<<1, 256, 0, stream>>>(bucketCnt, bucketOff, bucketCur, NB, E);
  k_bucket<<<EB, 256, 0, stream>>>(srcIdx, dstIdx, bucketOff, bucketCur, ebuf, E);
  k_csr<<<NB, 256, 0, stream>>>(ebuf, bucketOff, x, rowoff, col, dis, xd, N, E, NB);

  auto gemm = [&](const u16* Ain, int layer, int K, int Fo, u16* Cout) {
    int nby = cdiv(Fo, 128);
    k_gemm<<<nbx * nby, 256, 0, stream>>>(Ain, WTb + wtOff[layer], b[layer], Cout,
                                          psum, psq, N, K, Fo, nby);
    k_bnparams<<<cdiv(Fo, 4), 256, 0, stream>>>(psum, psq, Fo, nbx, N,
                                                g[layer], bt[layer], scaleF, shiftF);
  };

  const int waveGrid = cdiv(N * 64, 256);

  // ---- L1 (fully fused) ----
  k_l1<<<waveGrid, 256, 0, stream>>>(xd, rowoff, col, dis, W[0], b[0], Zb, N);
  {
    const int rowsPerChunk = 2048;
    const int nChunks = cdiv(N, rowsPerChunk);
    dim3 grid(nChunks, 1);
    k_colred<<<grid, 256, 0, stream>>>(Zb, 64, N, rowsPerChunk, psum, psq);
    k_bnparams<<<cdiv(64, 4), 256, 0, stream>>>(psum, psq, 64, nChunks, N, g[0], bt[0], scaleF, shiftF);
  }

  // ---- L2 (agg reads raw z + BN params) ----
  k_agg64<<<waveGrid, 256, 0, stream>>>(Zb, rowoff, col, dis, scaleF, shiftF, Ab, N);
  gemm(Ab, 1, 64, 64, Zb);

  // ---- L3 ----
  k_agg64<<<waveGrid, 256, 0, stream>>>(Zb, rowoff, col, dis, scaleF, shiftF, Ab, N);
  gemm(Ab, 2, 64, 256, Zb);

  // ---- L4 ----
  k_agg256<<<waveGrid, 256, 0, stream>>>(Zb, rowoff, col, dis, scaleF, shiftF, Ab, N);
  gemm(Ab, 3, 256, 256, Zb);

  // ---- L5 ----
  k_agg256<<<waveGrid, 256, 0, stream>>>(Zb, rowoff, col, dis, scaleF, shiftF, Ab, N);
  gemm(Ab, 4, 256, 512, Zb);

  // ---- L6 ----
  k_dot512<<<cdiv(N, 4), 256, 0, stream>>>(Zb, scaleF, shiftF, W[5], dis, vbuf, N);
  k_final<<<waveGrid, 256, 0, stream>>>(vbuf, rowoff, col, dis, b[5], (float*)d_out, N);
}